// Round 1
// baseline (662.920 us; speedup 1.0000x reference)
//
#include <hip/hip_runtime.h>

// RAConv: reciprocal-attention graph conv, N=100K nodes, E=1.6M edges, D=64, fp32.
// Strategy: counting-sort edges by dst (CSR), then wave-per-node register
// accumulation (zero float atomics), then fused fp32 epilogue GEMM.
//   attn normalization folded: msg = (sum_e x_src*exp(logit)) / (sum_e exp(logit))
//   var  = E[x^2] - E[x]^2   (exact rewrite of double scatter-mean)
//   softmax max-subtraction skipped: logits ~ N(0,1), no overflow risk.

static inline size_t ws_align(size_t x) { return (x + 255) & ~size_t(255); }

__global__ void hist_kernel(const int* __restrict__ ei, int* __restrict__ deg, int E) {
    int e = blockIdx.x * blockDim.x + threadIdx.x;
    if (e < E) atomicAdd(&deg[ei[E + e]], 1);
}

// Per-block exclusive scan (256 elems) + block sums.
__global__ void scan_a_kernel(const int* __restrict__ deg, int* __restrict__ rs,
                              int* __restrict__ bsum, int N) {
    __shared__ int t[256];
    int i = blockIdx.x * 256 + threadIdx.x;
    int v = (i < N) ? deg[i] : 0;
    t[threadIdx.x] = v;
    __syncthreads();
    for (int off = 1; off < 256; off <<= 1) {
        int u = (threadIdx.x >= (unsigned)off) ? t[threadIdx.x - off] : 0;
        __syncthreads();
        t[threadIdx.x] += u;
        __syncthreads();
    }
    if (i < N) rs[i] = t[threadIdx.x] - v;      // exclusive within block
    if (threadIdx.x == 255) bsum[blockIdx.x] = t[255];
}

// Exclusive scan of block sums (nb <= 512).
__global__ void scan_b_kernel(int* __restrict__ bsum, int nb) {
    __shared__ int t[512];
    int i = threadIdx.x;
    int v = (i < nb) ? bsum[i] : 0;
    t[i] = v;
    __syncthreads();
    for (int off = 1; off < 512; off <<= 1) {
        int u = (i >= off) ? t[i - off] : 0;
        __syncthreads();
        t[i] += u;
        __syncthreads();
    }
    if (i < nb) bsum[i] = t[i] - v;             // exclusive
}

__global__ void scan_c_kernel(int* __restrict__ rs, const int* __restrict__ bsum,
                              int* __restrict__ cursor, int N, int E) {
    int i = blockIdx.x * blockDim.x + threadIdx.x;
    if (i < N) {
        int v = rs[i] + bsum[i >> 8];
        rs[i] = v;
        cursor[i] = v;
    }
    if (i == 0) rs[N] = E;
}

__global__ void scatter_kernel(const int* __restrict__ ei, int* __restrict__ cursor,
                               int* __restrict__ srcs, int E) {
    int e = blockIdx.x * blockDim.x + threadIdx.x;
    if (e < E) {
        int dst = ei[E + e];
        int pos = atomicAdd(&cursor[dst], 1);
        srcs[pos] = ei[e];
    }
}

// One wave per node: iterate incoming edges, accumulate denom / sum_x / sum_x^2 /
// unnormalized msg entirely in registers. lane = feature index (D=64 = wave width).
__global__ void __launch_bounds__(256) node_gather_kernel(
        const float* __restrict__ x, const int* __restrict__ rs,
        const int* __restrict__ srcs, float* __restrict__ msgvar, int N) {
    int gid = blockIdx.x * blockDim.x + threadIdx.x;
    int w = gid >> 6;
    int lane = threadIdx.x & 63;
    if (w >= N) return;
    int s = rs[w], e = rs[w + 1];
    float xn = x[(size_t)w * 64 + lane];
    float den = 0.f, sx = 0.f, ssq = 0.f, sme = 0.f;
    for (int p = s; p < e; ++p) {
        int src = srcs[p];
        float xs = x[(size_t)src * 64 + lane];
        float t = xs * xn;
        #pragma unroll
        for (int off = 32; off > 0; off >>= 1) t += __shfl_xor(t, off, 64);
        float ex = __expf(t * 0.125f);            // scale = D^-0.5 = 1/8
        den += ex;
        sx  += xs;
        ssq += xs * xs;
        sme += xs * ex;
    }
    float c    = (float)(e - s);
    float cc   = fmaxf(c, 1.f);
    float mean = sx / cc;
    float var  = ssq / cc - mean * mean;          // E[x^2]-E[x]^2
    float msg  = (den > 0.f) ? (sme / den) : 0.f; // empty segment -> 0
    msgvar[(size_t)w * 128 + lane]      = msg;
    msgvar[(size_t)w * 128 + 64 + lane] = var;
}

// out[n][j] = sum_d x[n][d]*Ws[j][d] + msg[n][d]*Wn[j][d] + var[n][d]*Wv[j][d] + b
// Weights transposed+swizzled into LDS (2-way bank access = free); 4 nodes/wave
// amortize each LDS weight read; row values fetched via wave-uniform (scalar) loads.
__global__ void __launch_bounds__(256) gemm_kernel(
        const float* __restrict__ x, const float* __restrict__ msgvar,
        const float* __restrict__ Ws, const float* __restrict__ bs,
        const float* __restrict__ Wn, const float* __restrict__ bn,
        const float* __restrict__ Wv, const float* __restrict__ bv,
        float* __restrict__ out, int N) {
    __shared__ float WL[3 * 64 * 64];
    int tid = threadIdx.x;
    for (int idx = tid; idx < 3 * 4096; idx += 256) {
        int m = idx >> 12;
        int r = idx & 4095;
        int j = r >> 6, d = r & 63;
        const float* W = (m == 0) ? Ws : (m == 1) ? Wn : Wv;
        // store W[j][d] at [m][d][(j+d)&63]  -> conflict-free store & load
        WL[(m << 12) + (d << 6) + ((j + d) & 63)] = W[r];
    }
    __syncthreads();
    int lane = tid & 63;
    int wv = __builtin_amdgcn_readfirstlane(tid >> 6);   // force wave-uniform
    int nbase = blockIdx.x * 16 + wv * 4;
    float bsum = bs[lane] + bn[lane] + bv[lane];
    float acc0 = bsum, acc1 = bsum, acc2 = bsum, acc3 = bsum;
    int n0 = min(nbase + 0, N - 1);
    int n1 = min(nbase + 1, N - 1);
    int n2 = min(nbase + 2, N - 1);
    int n3 = min(nbase + 3, N - 1);
    #pragma unroll
    for (int m = 0; m < 3; ++m) {
        const float *p0, *p1, *p2, *p3;
        if (m == 0) {
            p0 = x + (size_t)n0 * 64; p1 = x + (size_t)n1 * 64;
            p2 = x + (size_t)n2 * 64; p3 = x + (size_t)n3 * 64;
        } else if (m == 1) {
            p0 = msgvar + (size_t)n0 * 128; p1 = msgvar + (size_t)n1 * 128;
            p2 = msgvar + (size_t)n2 * 128; p3 = msgvar + (size_t)n3 * 128;
        } else {
            p0 = msgvar + (size_t)n0 * 128 + 64; p1 = msgvar + (size_t)n1 * 128 + 64;
            p2 = msgvar + (size_t)n2 * 128 + 64; p3 = msgvar + (size_t)n3 * 128 + 64;
        }
        const float* wbase = &WL[m << 12];
        #pragma unroll
        for (int d = 0; d < 64; ++d) {
            float wgt = wbase[(d << 6) + ((lane + d) & 63)];
            acc0 = fmaf(p0[d], wgt, acc0);
            acc1 = fmaf(p1[d], wgt, acc1);
            acc2 = fmaf(p2[d], wgt, acc2);
            acc3 = fmaf(p3[d], wgt, acc3);
        }
    }
    if (nbase + 0 < N) out[(size_t)(nbase + 0) * 64 + lane] = acc0;
    if (nbase + 1 < N) out[(size_t)(nbase + 1) * 64 + lane] = acc1;
    if (nbase + 2 < N) out[(size_t)(nbase + 2) * 64 + lane] = acc2;
    if (nbase + 3 < N) out[(size_t)(nbase + 3) * 64 + lane] = acc3;
}

extern "C" void kernel_launch(void* const* d_in, const int* in_sizes, int n_in,
                              void* d_out, int out_size, void* d_ws, size_t ws_size,
                              hipStream_t stream) {
    const float* x  = (const float*)d_in[0];
    const int*   ei = (const int*)d_in[1];
    const float* Ws = (const float*)d_in[2];
    const float* bs = (const float*)d_in[3];
    const float* Wn = (const float*)d_in[4];
    const float* bn = (const float*)d_in[5];
    const float* Wv = (const float*)d_in[6];
    const float* bv = (const float*)d_in[7];
    float* out = (float*)d_out;

    int N  = in_sizes[0] / 64;
    int E  = in_sizes[1] / 2;
    int NB = (N + 255) / 256;

    char* wsp = (char*)d_ws;
    size_t off = 0;
    int* deg    = (int*)(wsp + off); off += ws_align((size_t)N * 4);
    int* rs     = (int*)(wsp + off); off += ws_align((size_t)(N + 1) * 4);
    int* cursor = (int*)(wsp + off); off += ws_align((size_t)N * 4);
    int* bsumi  = (int*)(wsp + off); off += ws_align((size_t)NB * 4);
    int* srcs   = (int*)(wsp + off); off += ws_align((size_t)E * 4);
    float* msgvar = (float*)(wsp + off); off += ws_align((size_t)N * 128 * 4);

    hipMemsetAsync(deg, 0, (size_t)N * 4, stream);
    hist_kernel<<<(E + 255) / 256, 256, 0, stream>>>(ei, deg, E);
    scan_a_kernel<<<NB, 256, 0, stream>>>(deg, rs, bsumi, N);
    scan_b_kernel<<<1, 512, 0, stream>>>(bsumi, NB);
    scan_c_kernel<<<(N + 255) / 256, 256, 0, stream>>>(rs, bsumi, cursor, N, E);
    scatter_kernel<<<(E + 255) / 256, 256, 0, stream>>>(ei, cursor, srcs, E);
    node_gather_kernel<<<((size_t)N * 64 + 255) / 256, 256, 0, stream>>>(x, rs, srcs, msgvar, N);
    gemm_kernel<<<(N + 15) / 16, 256, 0, stream>>>(x, msgvar, Ws, bs, Wn, bn, Wv, bv, out, N);
}

// Round 2
// 552.573 us; speedup vs baseline: 1.1997x; 1.1997x over previous
//
#include <hip/hip_runtime.h>

// RAConv: reciprocal-attention graph conv, N=100K nodes, E=1.6M edges, D=64, fp32.
// Strategy: counting-sort edges by dst (CSR), then wave-per-node register
// accumulation (zero float atomics), then fused fp32 epilogue GEMM.
//   attn normalization folded: msg = (sum_e x_src*exp(logit)) / (sum_e exp(logit))
//   var  = E[x^2] - E[x]^2   (exact rewrite of double scatter-mean)
//   softmax max-subtraction skipped: logits ~ N(0,1), no overflow risk.
// R2: node_gather restructured -> 2 edges per wave (32-lane halves, float2/lane),
//     5-step in-half reduce (DPP-speed masks), 2-pair ILP, 512B/load-instr.

static inline size_t ws_align(size_t x) { return (x + 255) & ~size_t(255); }

__global__ void hist_kernel(const int* __restrict__ ei, int* __restrict__ deg, int E) {
    int e = blockIdx.x * blockDim.x + threadIdx.x;
    if (e < E) atomicAdd(&deg[ei[E + e]], 1);
}

// Per-block exclusive scan (256 elems) + block sums.
__global__ void scan_a_kernel(const int* __restrict__ deg, int* __restrict__ rs,
                              int* __restrict__ bsum, int N) {
    __shared__ int t[256];
    int i = blockIdx.x * 256 + threadIdx.x;
    int v = (i < N) ? deg[i] : 0;
    t[threadIdx.x] = v;
    __syncthreads();
    for (int off = 1; off < 256; off <<= 1) {
        int u = (threadIdx.x >= (unsigned)off) ? t[threadIdx.x - off] : 0;
        __syncthreads();
        t[threadIdx.x] += u;
        __syncthreads();
    }
    if (i < N) rs[i] = t[threadIdx.x] - v;      // exclusive within block
    if (threadIdx.x == 255) bsum[blockIdx.x] = t[255];
}

// Exclusive scan of block sums (nb <= 512).
__global__ void scan_b_kernel(int* __restrict__ bsum, int nb) {
    __shared__ int t[512];
    int i = threadIdx.x;
    int v = (i < nb) ? bsum[i] : 0;
    t[i] = v;
    __syncthreads();
    for (int off = 1; off < 512; off <<= 1) {
        int u = (i >= off) ? t[i - off] : 0;
        __syncthreads();
        t[i] += u;
        __syncthreads();
    }
    if (i < nb) bsum[i] = t[i] - v;             // exclusive
}

__global__ void scan_c_kernel(int* __restrict__ rs, const int* __restrict__ bsum,
                              int* __restrict__ cursor, int N, int E) {
    int i = blockIdx.x * blockDim.x + threadIdx.x;
    if (i < N) {
        int v = rs[i] + bsum[i >> 8];
        rs[i] = v;
        cursor[i] = v;
    }
    if (i == 0) rs[N] = E;
}

__global__ void scatter_kernel(const int* __restrict__ ei, int* __restrict__ cursor,
                               int* __restrict__ srcs, int E) {
    int e = blockIdx.x * blockDim.x + threadIdx.x;
    if (e < E) {
        int dst = ei[E + e];
        int pos = atomicAdd(&cursor[dst], 1);
        srcs[pos] = ei[e];
    }
}

// One wave per node, 2 edges processed concurrently (lanes 0-31 = edge A,
// lanes 32-63 = edge B, each lane holds a float2 feature pair). Dot product
// reduces in 5 xor-shuffle steps within each 32-lane half (masks<=16 -> DPP).
// Main loop does 2 pairs (4 edges) per iteration for ILP. Cross-half combine
// once per node at the end.
__global__ void __launch_bounds__(256) node_gather_kernel(
        const float* __restrict__ x, const int* __restrict__ rs,
        const int* __restrict__ srcs, float* __restrict__ msgvar, int N) {
    int gid = blockIdx.x * blockDim.x + threadIdx.x;
    int w = gid >> 6;
    if (w >= N) return;
    int lane = threadIdx.x & 63;
    int k = lane & 31;                 // feature-pair index (features 2k, 2k+1)
    int half = lane >> 5;              // which edge of the pair this lane serves
    int s = rs[w], e = rs[w + 1];
    const float2* x2 = (const float2*)x;
    float2 xn = x2[(size_t)w * 32 + k];
    float den = 0.f;
    float2 sx = {0.f, 0.f}, ssq = {0.f, 0.f}, sme = {0.f, 0.f};
    int p = s;
    // main loop: 4 edges per iteration (2 independent pair-chains)
    for (; p + 4 <= e; p += 4) {
        int iA0 = srcs[p + 0], iB0 = srcs[p + 1];
        int iA1 = srcs[p + 2], iB1 = srcs[p + 3];
        int r0 = half ? iB0 : iA0;
        int r1 = half ? iB1 : iA1;
        float2 v0 = x2[(size_t)r0 * 32 + k];
        float2 v1 = x2[(size_t)r1 * 32 + k];
        float t0 = fmaf(v0.x, xn.x, v0.y * xn.y);
        float t1 = fmaf(v1.x, xn.x, v1.y * xn.y);
        #pragma unroll
        for (int off = 1; off < 32; off <<= 1) {
            t0 += __shfl_xor(t0, off, 64);
            t1 += __shfl_xor(t1, off, 64);
        }
        float ex0 = __expf(t0 * 0.125f);
        float ex1 = __expf(t1 * 0.125f);
        den += ex0 + ex1;
        sx.x += v0.x + v1.x;            sx.y += v0.y + v1.y;
        ssq.x = fmaf(v0.x, v0.x, ssq.x); ssq.y = fmaf(v0.y, v0.y, ssq.y);
        ssq.x = fmaf(v1.x, v1.x, ssq.x); ssq.y = fmaf(v1.y, v1.y, ssq.y);
        sme.x = fmaf(ex0, v0.x, sme.x);  sme.y = fmaf(ex0, v0.y, sme.y);
        sme.x = fmaf(ex1, v1.x, sme.x);  sme.y = fmaf(ex1, v1.y, sme.y);
    }
    // pair tail (2 edges)
    if (p + 2 <= e) {
        int iA = srcs[p], iB = srcs[p + 1];
        int r = half ? iB : iA;
        float2 v = x2[(size_t)r * 32 + k];
        float t = fmaf(v.x, xn.x, v.y * xn.y);
        #pragma unroll
        for (int off = 1; off < 32; off <<= 1) t += __shfl_xor(t, off, 64);
        float ex = __expf(t * 0.125f);
        den += ex;
        sx.x += v.x; sx.y += v.y;
        ssq.x = fmaf(v.x, v.x, ssq.x); ssq.y = fmaf(v.y, v.y, ssq.y);
        sme.x = fmaf(ex, v.x, sme.x);  sme.y = fmaf(ex, v.y, sme.y);
        p += 2;
    }
    // single-edge tail: both halves see the same edge; weight half 1 to zero
    // so the cross-half combine doesn't double-count.
    if (p < e) {
        int r = srcs[p];
        float2 v = x2[(size_t)r * 32 + k];
        float t = fmaf(v.x, xn.x, v.y * xn.y);
        #pragma unroll
        for (int off = 1; off < 32; off <<= 1) t += __shfl_xor(t, off, 64);
        float wt = (half == 0) ? 1.f : 0.f;
        float ex = __expf(t * 0.125f) * wt;
        float vx = v.x * wt, vy = v.y * wt;
        den += ex;
        sx.x += vx; sx.y += vy;
        ssq.x = fmaf(vx, v.x, ssq.x); ssq.y = fmaf(vy, v.y, ssq.y);
        sme.x = fmaf(ex, v.x, sme.x); sme.y = fmaf(ex, v.y, sme.y);
    }
    // combine the two 32-lane halves (lane l and l^32 hold the same k)
    den   += __shfl_xor(den,   32, 64);
    sx.x  += __shfl_xor(sx.x,  32, 64);
    sx.y  += __shfl_xor(sx.y,  32, 64);
    ssq.x += __shfl_xor(ssq.x, 32, 64);
    ssq.y += __shfl_xor(ssq.y, 32, 64);
    sme.x += __shfl_xor(sme.x, 32, 64);
    sme.y += __shfl_xor(sme.y, 32, 64);
    float c  = (float)(e - s);
    float inv = 1.f / fmaxf(c, 1.f);
    float mx = sx.x * inv, my = sx.y * inv;
    float2 var; var.x = ssq.x * inv - mx * mx; var.y = ssq.y * inv - my * my;
    float invden = (den > 0.f) ? (1.f / den) : 0.f;
    float2 msg; msg.x = sme.x * invden; msg.y = sme.y * invden;
    if (lane < 32) {
        float2* mv = (float2*)(msgvar + (size_t)w * 128);
        mv[k]      = msg;
        mv[32 + k] = var;
    }
}

// out[n][j] = sum_d x[n][d]*Ws[j][d] + msg[n][d]*Wn[j][d] + var[n][d]*Wv[j][d] + b
// Weights transposed+swizzled into LDS (2-way bank access = free); 4 nodes/wave
// amortize each LDS weight read; row values fetched via wave-uniform (scalar) loads.
__global__ void __launch_bounds__(256) gemm_kernel(
        const float* __restrict__ x, const float* __restrict__ msgvar,
        const float* __restrict__ Ws, const float* __restrict__ bs,
        const float* __restrict__ Wn, const float* __restrict__ bn,
        const float* __restrict__ Wv, const float* __restrict__ bv,
        float* __restrict__ out, int N) {
    __shared__ float WL[3 * 64 * 64];
    int tid = threadIdx.x;
    for (int idx = tid; idx < 3 * 4096; idx += 256) {
        int m = idx >> 12;
        int r = idx & 4095;
        int j = r >> 6, d = r & 63;
        const float* W = (m == 0) ? Ws : (m == 1) ? Wn : Wv;
        // store W[j][d] at [m][d][(j+d)&63]  -> conflict-free store & load
        WL[(m << 12) + (d << 6) + ((j + d) & 63)] = W[r];
    }
    __syncthreads();
    int lane = tid & 63;
    int wv = __builtin_amdgcn_readfirstlane(tid >> 6);   // force wave-uniform
    int nbase = blockIdx.x * 16 + wv * 4;
    float bsum = bs[lane] + bn[lane] + bv[lane];
    float acc0 = bsum, acc1 = bsum, acc2 = bsum, acc3 = bsum;
    int n0 = min(nbase + 0, N - 1);
    int n1 = min(nbase + 1, N - 1);
    int n2 = min(nbase + 2, N - 1);
    int n3 = min(nbase + 3, N - 1);
    #pragma unroll
    for (int m = 0; m < 3; ++m) {
        const float *p0, *p1, *p2, *p3;
        if (m == 0) {
            p0 = x + (size_t)n0 * 64; p1 = x + (size_t)n1 * 64;
            p2 = x + (size_t)n2 * 64; p3 = x + (size_t)n3 * 64;
        } else if (m == 1) {
            p0 = msgvar + (size_t)n0 * 128; p1 = msgvar + (size_t)n1 * 128;
            p2 = msgvar + (size_t)n2 * 128; p3 = msgvar + (size_t)n3 * 128;
        } else {
            p0 = msgvar + (size_t)n0 * 128 + 64; p1 = msgvar + (size_t)n1 * 128 + 64;
            p2 = msgvar + (size_t)n2 * 128 + 64; p3 = msgvar + (size_t)n3 * 128 + 64;
        }
        const float* wbase = &WL[m << 12];
        #pragma unroll
        for (int d = 0; d < 64; ++d) {
            float wgt = wbase[(d << 6) + ((lane + d) & 63)];
            acc0 = fmaf(p0[d], wgt, acc0);
            acc1 = fmaf(p1[d], wgt, acc1);
            acc2 = fmaf(p2[d], wgt, acc2);
            acc3 = fmaf(p3[d], wgt, acc3);
        }
    }
    if (nbase + 0 < N) out[(size_t)(nbase + 0) * 64 + lane] = acc0;
    if (nbase + 1 < N) out[(size_t)(nbase + 1) * 64 + lane] = acc1;
    if (nbase + 2 < N) out[(size_t)(nbase + 2) * 64 + lane] = acc2;
    if (nbase + 3 < N) out[(size_t)(nbase + 3) * 64 + lane] = acc3;
}

extern "C" void kernel_launch(void* const* d_in, const int* in_sizes, int n_in,
                              void* d_out, int out_size, void* d_ws, size_t ws_size,
                              hipStream_t stream) {
    const float* x  = (const float*)d_in[0];
    const int*   ei = (const int*)d_in[1];
    const float* Ws = (const float*)d_in[2];
    const float* bs = (const float*)d_in[3];
    const float* Wn = (const float*)d_in[4];
    const float* bn = (const float*)d_in[5];
    const float* Wv = (const float*)d_in[6];
    const float* bv = (const float*)d_in[7];
    float* out = (float*)d_out;

    int N  = in_sizes[0] / 64;
    int E  = in_sizes[1] / 2;
    int NB = (N + 255) / 256;

    char* wsp = (char*)d_ws;
    size_t off = 0;
    int* deg    = (int*)(wsp + off); off += ws_align((size_t)N * 4);
    int* rs     = (int*)(wsp + off); off += ws_align((size_t)(N + 1) * 4);
    int* cursor = (int*)(wsp + off); off += ws_align((size_t)N * 4);
    int* bsumi  = (int*)(wsp + off); off += ws_align((size_t)NB * 4);
    int* srcs   = (int*)(wsp + off); off += ws_align((size_t)E * 4);
    float* msgvar = (float*)(wsp + off); off += ws_align((size_t)N * 128 * 4);

    hipMemsetAsync(deg, 0, (size_t)N * 4, stream);
    hist_kernel<<<(E + 255) / 256, 256, 0, stream>>>(ei, deg, E);
    scan_a_kernel<<<NB, 256, 0, stream>>>(deg, rs, bsumi, N);
    scan_b_kernel<<<1, 512, 0, stream>>>(bsumi, NB);
    scan_c_kernel<<<(N + 255) / 256, 256, 0, stream>>>(rs, bsumi, cursor, N, E);
    scatter_kernel<<<(E + 255) / 256, 256, 0, stream>>>(ei, cursor, srcs, E);
    node_gather_kernel<<<((size_t)N * 64 + 255) / 256, 256, 0, stream>>>(x, rs, srcs, msgvar, N);
    gemm_kernel<<<(N + 15) / 16, 256, 0, stream>>>(x, msgvar, Ws, bs, Wn, bn, Wv, bv, out, N);
}

// Round 3
// 393.942 us; speedup vs baseline: 1.6828x; 1.4027x over previous
//
#include <hip/hip_runtime.h>

// RAConv: reciprocal-attention graph conv, N=100K nodes, E=1.6M edges, D=64, fp32.
// Strategy: counting-sort edges by dst (CSR), then wave-per-node register
// accumulation (zero float atomics), then fused bf16-MFMA epilogue GEMM.
//   attn normalization folded: msg = (sum_e x_src*exp(logit)) / (sum_e exp(logit))
//   var  = E[x^2] - E[x]^2   (exact rewrite of double scatter-mean)
// R2: node_gather -> 2 edges/wave split-half layout (float2/lane, 5-step reduce).
// R3: gemm -> mfma_f32_16x16x32_bf16; A=[x|msg|var] (N x 192) staged bf16 in LDS
//     (row pad 200 shorts = conflict-free b128 frags), W frags in VGPRs,
//     4 feature-tiles/block (1 per wave), 4 node-tiles of 16. fp32 accumulate.

static inline size_t ws_align(size_t x) { return (x + 255) & ~size_t(255); }

typedef __attribute__((ext_vector_type(8))) short bf16x8;
typedef __attribute__((ext_vector_type(4))) float f32x4;

__device__ __forceinline__ unsigned short f2bf(float f) {
    unsigned u = __builtin_bit_cast(unsigned, f);
    u += 0x7FFFu + ((u >> 16) & 1u);          // RNE
    return (unsigned short)(u >> 16);
}

__global__ void hist_kernel(const int* __restrict__ ei, int* __restrict__ deg, int E) {
    int e = blockIdx.x * blockDim.x + threadIdx.x;
    if (e < E) atomicAdd(&deg[ei[E + e]], 1);
}

// Per-block exclusive scan (256 elems) + block sums.
__global__ void scan_a_kernel(const int* __restrict__ deg, int* __restrict__ rs,
                              int* __restrict__ bsum, int N) {
    __shared__ int t[256];
    int i = blockIdx.x * 256 + threadIdx.x;
    int v = (i < N) ? deg[i] : 0;
    t[threadIdx.x] = v;
    __syncthreads();
    for (int off = 1; off < 256; off <<= 1) {
        int u = (threadIdx.x >= (unsigned)off) ? t[threadIdx.x - off] : 0;
        __syncthreads();
        t[threadIdx.x] += u;
        __syncthreads();
    }
    if (i < N) rs[i] = t[threadIdx.x] - v;      // exclusive within block
    if (threadIdx.x == 255) bsum[blockIdx.x] = t[255];
}

// Exclusive scan of block sums (nb <= 512).
__global__ void scan_b_kernel(int* __restrict__ bsum, int nb) {
    __shared__ int t[512];
    int i = threadIdx.x;
    int v = (i < nb) ? bsum[i] : 0;
    t[i] = v;
    __syncthreads();
    for (int off = 1; off < 512; off <<= 1) {
        int u = (i >= off) ? t[i - off] : 0;
        __syncthreads();
        t[i] += u;
        __syncthreads();
    }
    if (i < nb) bsum[i] = t[i] - v;             // exclusive
}

__global__ void scan_c_kernel(int* __restrict__ rs, const int* __restrict__ bsum,
                              int* __restrict__ cursor, int N, int E) {
    int i = blockIdx.x * blockDim.x + threadIdx.x;
    if (i < N) {
        int v = rs[i] + bsum[i >> 8];
        rs[i] = v;
        cursor[i] = v;
    }
    if (i == 0) rs[N] = E;
}

__global__ void scatter_kernel(const int* __restrict__ ei, int* __restrict__ cursor,
                               int* __restrict__ srcs, int E) {
    int e = blockIdx.x * blockDim.x + threadIdx.x;
    if (e < E) {
        int dst = ei[E + e];
        int pos = atomicAdd(&cursor[dst], 1);
        srcs[pos] = ei[e];
    }
}

// One wave per node, 2 edges processed concurrently (lanes 0-31 = edge A,
// lanes 32-63 = edge B, each lane holds a float2 feature pair). Dot product
// reduces in 5 xor-shuffle steps within each 32-lane half (masks<=16 -> DPP).
// Main loop does 2 pairs (4 edges) per iteration for ILP. Cross-half combine
// once per node at the end.
__global__ void __launch_bounds__(256) node_gather_kernel(
        const float* __restrict__ x, const int* __restrict__ rs,
        const int* __restrict__ srcs, float* __restrict__ msgvar, int N) {
    int gid = blockIdx.x * blockDim.x + threadIdx.x;
    int w = gid >> 6;
    if (w >= N) return;
    int lane = threadIdx.x & 63;
    int k = lane & 31;                 // feature-pair index (features 2k, 2k+1)
    int half = lane >> 5;              // which edge of the pair this lane serves
    int s = rs[w], e = rs[w + 1];
    const float2* x2 = (const float2*)x;
    float2 xn = x2[(size_t)w * 32 + k];
    float den = 0.f;
    float2 sx = {0.f, 0.f}, ssq = {0.f, 0.f}, sme = {0.f, 0.f};
    int p = s;
    // main loop: 4 edges per iteration (2 independent pair-chains)
    for (; p + 4 <= e; p += 4) {
        int iA0 = srcs[p + 0], iB0 = srcs[p + 1];
        int iA1 = srcs[p + 2], iB1 = srcs[p + 3];
        int r0 = half ? iB0 : iA0;
        int r1 = half ? iB1 : iA1;
        float2 v0 = x2[(size_t)r0 * 32 + k];
        float2 v1 = x2[(size_t)r1 * 32 + k];
        float t0 = fmaf(v0.x, xn.x, v0.y * xn.y);
        float t1 = fmaf(v1.x, xn.x, v1.y * xn.y);
        #pragma unroll
        for (int off = 1; off < 32; off <<= 1) {
            t0 += __shfl_xor(t0, off, 64);
            t1 += __shfl_xor(t1, off, 64);
        }
        float ex0 = __expf(t0 * 0.125f);
        float ex1 = __expf(t1 * 0.125f);
        den += ex0 + ex1;
        sx.x += v0.x + v1.x;            sx.y += v0.y + v1.y;
        ssq.x = fmaf(v0.x, v0.x, ssq.x); ssq.y = fmaf(v0.y, v0.y, ssq.y);
        ssq.x = fmaf(v1.x, v1.x, ssq.x); ssq.y = fmaf(v1.y, v1.y, ssq.y);
        sme.x = fmaf(ex0, v0.x, sme.x);  sme.y = fmaf(ex0, v0.y, sme.y);
        sme.x = fmaf(ex1, v1.x, sme.x);  sme.y = fmaf(ex1, v1.y, sme.y);
    }
    // pair tail (2 edges)
    if (p + 2 <= e) {
        int iA = srcs[p], iB = srcs[p + 1];
        int r = half ? iB : iA;
        float2 v = x2[(size_t)r * 32 + k];
        float t = fmaf(v.x, xn.x, v.y * xn.y);
        #pragma unroll
        for (int off = 1; off < 32; off <<= 1) t += __shfl_xor(t, off, 64);
        float ex = __expf(t * 0.125f);
        den += ex;
        sx.x += v.x; sx.y += v.y;
        ssq.x = fmaf(v.x, v.x, ssq.x); ssq.y = fmaf(v.y, v.y, ssq.y);
        sme.x = fmaf(ex, v.x, sme.x);  sme.y = fmaf(ex, v.y, sme.y);
        p += 2;
    }
    // single-edge tail: both halves see the same edge; weight half 1 to zero
    // so the cross-half combine doesn't double-count.
    if (p < e) {
        int r = srcs[p];
        float2 v = x2[(size_t)r * 32 + k];
        float t = fmaf(v.x, xn.x, v.y * xn.y);
        #pragma unroll
        for (int off = 1; off < 32; off <<= 1) t += __shfl_xor(t, off, 64);
        float wt = (half == 0) ? 1.f : 0.f;
        float ex = __expf(t * 0.125f) * wt;
        float vx = v.x * wt, vy = v.y * wt;
        den += ex;
        sx.x += vx; sx.y += vy;
        ssq.x = fmaf(vx, v.x, ssq.x); ssq.y = fmaf(vy, v.y, ssq.y);
        sme.x = fmaf(ex, v.x, sme.x); sme.y = fmaf(ex, v.y, sme.y);
    }
    // combine the two 32-lane halves (lane l and l^32 hold the same k)
    den   += __shfl_xor(den,   32, 64);
    sx.x  += __shfl_xor(sx.x,  32, 64);
    sx.y  += __shfl_xor(sx.y,  32, 64);
    ssq.x += __shfl_xor(ssq.x, 32, 64);
    ssq.y += __shfl_xor(ssq.y, 32, 64);
    sme.x += __shfl_xor(sme.x, 32, 64);
    sme.y += __shfl_xor(sme.y, 32, 64);
    float c  = (float)(e - s);
    float inv = 1.f / fmaxf(c, 1.f);
    float mx = sx.x * inv, my = sx.y * inv;
    float2 var; var.x = ssq.x * inv - mx * mx; var.y = ssq.y * inv - my * my;
    float invden = (den > 0.f) ? (1.f / den) : 0.f;
    float2 msg; msg.x = sme.x * invden; msg.y = sme.y * invden;
    if (lane < 32) {
        float2* mv = (float2*)(msgvar + (size_t)w * 128);
        mv[k]      = msg;
        mv[32 + k] = var;
    }
}

// MFMA epilogue GEMM: out = A @ Wcat^T + b, A = [x | msg | var] (N x 192).
// Block = 256 thr = 4 waves, covers 64 nodes. A-tile staged bf16 in LDS
// (64 rows x 200-short pitch). Wave w owns feature tile w (16 cols); B-frags
// (weights bf16) live in 24 VGPRs; 4 node-tiles x 6 K-steps of
// mfma_f32_16x16x32_bf16. Layouts per verified m89/m120 mappings:
//   A: lane holds A[m=lane&15][k=quad*8+j]; B: lane holds B[k=quad*8+j][n=lane&15]
//   D: col=lane&15, row=quad*4+reg.
__global__ void __launch_bounds__(256) gemm_kernel(
        const float* __restrict__ x, const float* __restrict__ msgvar,
        const float* __restrict__ Ws, const float* __restrict__ bs,
        const float* __restrict__ Wn, const float* __restrict__ bn,
        const float* __restrict__ Wv, const float* __restrict__ bv,
        float* __restrict__ out, int N) {
    __shared__ unsigned short As[64 * 200];
    int tid = threadIdx.x;
    int nbase = blockIdx.x * 64;

    // stage x part: 64 rows x 16 float4
    #pragma unroll
    for (int i = 0; i < 4; ++i) {
        int idx = i * 256 + tid;
        int row = idx >> 4, c = idx & 15;
        int n = min(nbase + row, N - 1);
        float4 v = ((const float4*)(x + (size_t)n * 64))[c];
        ushort4 h; h.x = f2bf(v.x); h.y = f2bf(v.y); h.z = f2bf(v.z); h.w = f2bf(v.w);
        *(ushort4*)&As[row * 200 + c * 4] = h;
    }
    // stage msgvar part: 64 rows x 32 float4 (msg then var, contiguous per node)
    #pragma unroll
    for (int i = 0; i < 8; ++i) {
        int idx = i * 256 + tid;
        int row = idx >> 5, c = idx & 31;
        int n = min(nbase + row, N - 1);
        float4 v = ((const float4*)(msgvar + (size_t)n * 128))[c];
        ushort4 h; h.x = f2bf(v.x); h.y = f2bf(v.y); h.z = f2bf(v.z); h.w = f2bf(v.w);
        *(ushort4*)&As[row * 200 + 64 + c * 4] = h;
    }

    int lane = tid & 63;
    int wv = tid >> 6;                  // feature tile (wave id)
    int j = lane & 15, quad = lane >> 4;
    int jg = wv * 16 + j;               // global output feature

    // B fragments: 6 K-steps, lane holds W[jg][k0..k0+7] as bf16
    const float* Wm0[3] = {Ws, Wn, Wv};
    bf16x8 bfrag[6];
    #pragma unroll
    for (int ks = 0; ks < 6; ++ks) {
        const float* W = Wm0[ks >> 1];
        int k0 = (ks & 1) * 32 + quad * 8;
        const float4* p = (const float4*)(W + (size_t)jg * 64 + k0);
        float4 a = p[0], b = p[1];
        bf16x8 f;
        f[0] = (short)f2bf(a.x); f[1] = (short)f2bf(a.y);
        f[2] = (short)f2bf(a.z); f[3] = (short)f2bf(a.w);
        f[4] = (short)f2bf(b.x); f[5] = (short)f2bf(b.y);
        f[6] = (short)f2bf(b.z); f[7] = (short)f2bf(b.w);
        bfrag[ks] = f;
    }
    float bias = bs[jg] + bn[jg] + bv[jg];
    f32x4 acc[4];
    #pragma unroll
    for (int nt = 0; nt < 4; ++nt) { acc[nt][0] = bias; acc[nt][1] = bias; acc[nt][2] = bias; acc[nt][3] = bias; }

    __syncthreads();

    #pragma unroll
    for (int nt = 0; nt < 4; ++nt) {
        #pragma unroll
        for (int ks = 0; ks < 6; ++ks) {
            const bf16x8* ap = (const bf16x8*)&As[(nt * 16 + j) * 200 + ks * 32 + quad * 8];
            acc[nt] = __builtin_amdgcn_mfma_f32_16x16x32_bf16(*ap, bfrag[ks], acc[nt], 0, 0, 0);
        }
    }

    // D: node = nbase + nt*16 + quad*4 + r, col = jg
    #pragma unroll
    for (int nt = 0; nt < 4; ++nt) {
        #pragma unroll
        for (int r = 0; r < 4; ++r) {
            int node = nbase + nt * 16 + quad * 4 + r;
            if (node < N) out[(size_t)node * 64 + jg] = acc[nt][r];
        }
    }
}

extern "C" void kernel_launch(void* const* d_in, const int* in_sizes, int n_in,
                              void* d_out, int out_size, void* d_ws, size_t ws_size,
                              hipStream_t stream) {
    const float* x  = (const float*)d_in[0];
    const int*   ei = (const int*)d_in[1];
    const float* Ws = (const float*)d_in[2];
    const float* bs = (const float*)d_in[3];
    const float* Wn = (const float*)d_in[4];
    const float* bn = (const float*)d_in[5];
    const float* Wv = (const float*)d_in[6];
    const float* bv = (const float*)d_in[7];
    float* out = (float*)d_out;

    int N  = in_sizes[0] / 64;
    int E  = in_sizes[1] / 2;
    int NB = (N + 255) / 256;

    char* wsp = (char*)d_ws;
    size_t off = 0;
    int* deg    = (int*)(wsp + off); off += ws_align((size_t)N * 4);
    int* rs     = (int*)(wsp + off); off += ws_align((size_t)(N + 1) * 4);
    int* cursor = (int*)(wsp + off); off += ws_align((size_t)N * 4);
    int* bsumi  = (int*)(wsp + off); off += ws_align((size_t)NB * 4);
    int* srcs   = (int*)(wsp + off); off += ws_align((size_t)E * 4);
    float* msgvar = (float*)(wsp + off); off += ws_align((size_t)N * 128 * 4);

    hipMemsetAsync(deg, 0, (size_t)N * 4, stream);
    hist_kernel<<<(E + 255) / 256, 256, 0, stream>>>(ei, deg, E);
    scan_a_kernel<<<NB, 256, 0, stream>>>(deg, rs, bsumi, N);
    scan_b_kernel<<<1, 512, 0, stream>>>(bsumi, NB);
    scan_c_kernel<<<(N + 255) / 256, 256, 0, stream>>>(rs, bsumi, cursor, N, E);
    scatter_kernel<<<(E + 255) / 256, 256, 0, stream>>>(ei, cursor, srcs, E);
    node_gather_kernel<<<((size_t)N * 64 + 255) / 256, 256, 0, stream>>>(x, rs, srcs, msgvar, N);
    gemm_kernel<<<(N + 63) / 64, 256, 0, stream>>>(x, msgvar, Ws, bs, Wn, bn, Wv, bv, out, N);
}

// Round 4
// 336.657 us; speedup vs baseline: 1.9691x; 1.1702x over previous
//
#include <hip/hip_runtime.h>

// RAConv: reciprocal-attention graph conv, N=100K nodes, E=1.6M edges, D=64, fp32.
// Strategy: counting-sort edges by dst (CSR), then wave-per-node register
// accumulation (zero float atomics), then fused bf16-MFMA epilogue GEMM.
//   attn normalization folded: msg = (sum_e x_src*exp(logit)) / (sum_e exp(logit))
//   var  = E[x^2] - E[x]^2   (exact rewrite of double scatter-mean)
// R2: node_gather -> 2 edges/wave split-half layout (float2/lane, 5-step reduce).
// R3: gemm -> mfma_f32_16x16x32_bf16, A=[x|msg|var] staged bf16 in LDS.
// R4: hist+scatter XCD-partitioned (part = blockIdx&7 handles dst range
//     [part*N/8,(part+1)*N/8)): cursor atomics + srcs lines become single-XCD
//     -> L2-local atomics, full-line write combining (WRITE_SIZE 106MB -> ~12MB).

static inline size_t ws_align(size_t x) { return (x + 255) & ~size_t(255); }

typedef __attribute__((ext_vector_type(8))) short bf16x8;
typedef __attribute__((ext_vector_type(4))) float f32x4;

__device__ __forceinline__ unsigned short f2bf(float f) {
    unsigned u = __builtin_bit_cast(unsigned, f);
    u += 0x7FFFu + ((u >> 16) & 1u);          // RNE
    return (unsigned short)(u >> 16);
}

// Partitioned histogram: only edges whose dst falls in this block's partition.
__global__ void __launch_bounds__(256) hist_kernel(const int* __restrict__ ei,
                                                   int* __restrict__ deg, int E, int N) {
    int part = blockIdx.x & 7;
    int vb   = blockIdx.x >> 3;
    int nvb  = gridDim.x >> 3;
    const int* dstp = ei + E;
    for (int base = vb * 256; base < E; base += nvb * 256) {
        int e = base + threadIdx.x;
        if (e < E) {
            int dst = dstp[e];
            int p = (int)(((long long)dst * 8) / N);
            if (p == part) atomicAdd(&deg[dst], 1);
        }
    }
}

// Per-block exclusive scan (256 elems) + block sums.
__global__ void scan_a_kernel(const int* __restrict__ deg, int* __restrict__ rs,
                              int* __restrict__ bsum, int N) {
    __shared__ int t[256];
    int i = blockIdx.x * 256 + threadIdx.x;
    int v = (i < N) ? deg[i] : 0;
    t[threadIdx.x] = v;
    __syncthreads();
    for (int off = 1; off < 256; off <<= 1) {
        int u = (threadIdx.x >= (unsigned)off) ? t[threadIdx.x - off] : 0;
        __syncthreads();
        t[threadIdx.x] += u;
        __syncthreads();
    }
    if (i < N) rs[i] = t[threadIdx.x] - v;      // exclusive within block
    if (threadIdx.x == 255) bsum[blockIdx.x] = t[255];
}

// Exclusive scan of block sums (nb <= 512).
__global__ void scan_b_kernel(int* __restrict__ bsum, int nb) {
    __shared__ int t[512];
    int i = threadIdx.x;
    int v = (i < nb) ? bsum[i] : 0;
    t[i] = v;
    __syncthreads();
    for (int off = 1; off < 512; off <<= 1) {
        int u = (i >= off) ? t[i - off] : 0;
        __syncthreads();
        t[i] += u;
        __syncthreads();
    }
    if (i < nb) bsum[i] = t[i] - v;             // exclusive
}

__global__ void scan_c_kernel(int* __restrict__ rs, const int* __restrict__ bsum,
                              int* __restrict__ cursor, int N, int E) {
    int i = blockIdx.x * blockDim.x + threadIdx.x;
    if (i < N) {
        int v = rs[i] + bsum[i >> 8];
        rs[i] = v;
        cursor[i] = v;
    }
    if (i == 0) rs[N] = E;
}

// Partitioned scatter: same partition rule as hist -> cursor + srcs region for
// a dst range is touched by one partition's blocks only (one XCD under the
// round-robin mapping; correctness does not depend on the mapping).
__global__ void __launch_bounds__(256) scatter_kernel(const int* __restrict__ ei,
                                                      int* __restrict__ cursor,
                                                      int* __restrict__ srcs, int E, int N) {
    int part = blockIdx.x & 7;
    int vb   = blockIdx.x >> 3;
    int nvb  = gridDim.x >> 3;
    const int* dstp = ei + E;
    for (int base = vb * 256; base < E; base += nvb * 256) {
        int e = base + threadIdx.x;
        if (e < E) {
            int dst = dstp[e];
            int p = (int)(((long long)dst * 8) / N);
            if (p == part) {
                int pos = atomicAdd(&cursor[dst], 1);
                srcs[pos] = ei[e];
            }
        }
    }
}

// One wave per node, 2 edges processed concurrently (lanes 0-31 = edge A,
// lanes 32-63 = edge B, each lane holds a float2 feature pair). Dot product
// reduces in 5 xor-shuffle steps within each 32-lane half (masks<=16 -> DPP).
// Main loop does 2 pairs (4 edges) per iteration for ILP. Cross-half combine
// once per node at the end.
__global__ void __launch_bounds__(256) node_gather_kernel(
        const float* __restrict__ x, const int* __restrict__ rs,
        const int* __restrict__ srcs, float* __restrict__ msgvar, int N) {
    int gid = blockIdx.x * blockDim.x + threadIdx.x;
    int w = gid >> 6;
    if (w >= N) return;
    int lane = threadIdx.x & 63;
    int k = lane & 31;                 // feature-pair index (features 2k, 2k+1)
    int half = lane >> 5;              // which edge of the pair this lane serves
    int s = rs[w], e = rs[w + 1];
    const float2* x2 = (const float2*)x;
    float2 xn = x2[(size_t)w * 32 + k];
    float den = 0.f;
    float2 sx = {0.f, 0.f}, ssq = {0.f, 0.f}, sme = {0.f, 0.f};
    int p = s;
    // main loop: 4 edges per iteration (2 independent pair-chains)
    for (; p + 4 <= e; p += 4) {
        int iA0 = srcs[p + 0], iB0 = srcs[p + 1];
        int iA1 = srcs[p + 2], iB1 = srcs[p + 3];
        int r0 = half ? iB0 : iA0;
        int r1 = half ? iB1 : iA1;
        float2 v0 = x2[(size_t)r0 * 32 + k];
        float2 v1 = x2[(size_t)r1 * 32 + k];
        float t0 = fmaf(v0.x, xn.x, v0.y * xn.y);
        float t1 = fmaf(v1.x, xn.x, v1.y * xn.y);
        #pragma unroll
        for (int off = 1; off < 32; off <<= 1) {
            t0 += __shfl_xor(t0, off, 64);
            t1 += __shfl_xor(t1, off, 64);
        }
        float ex0 = __expf(t0 * 0.125f);
        float ex1 = __expf(t1 * 0.125f);
        den += ex0 + ex1;
        sx.x += v0.x + v1.x;            sx.y += v0.y + v1.y;
        ssq.x = fmaf(v0.x, v0.x, ssq.x); ssq.y = fmaf(v0.y, v0.y, ssq.y);
        ssq.x = fmaf(v1.x, v1.x, ssq.x); ssq.y = fmaf(v1.y, v1.y, ssq.y);
        sme.x = fmaf(ex0, v0.x, sme.x);  sme.y = fmaf(ex0, v0.y, sme.y);
        sme.x = fmaf(ex1, v1.x, sme.x);  sme.y = fmaf(ex1, v1.y, sme.y);
    }
    // pair tail (2 edges)
    if (p + 2 <= e) {
        int iA = srcs[p], iB = srcs[p + 1];
        int r = half ? iB : iA;
        float2 v = x2[(size_t)r * 32 + k];
        float t = fmaf(v.x, xn.x, v.y * xn.y);
        #pragma unroll
        for (int off = 1; off < 32; off <<= 1) t += __shfl_xor(t, off, 64);
        float ex = __expf(t * 0.125f);
        den += ex;
        sx.x += v.x; sx.y += v.y;
        ssq.x = fmaf(v.x, v.x, ssq.x); ssq.y = fmaf(v.y, v.y, ssq.y);
        sme.x = fmaf(ex, v.x, sme.x);  sme.y = fmaf(ex, v.y, sme.y);
        p += 2;
    }
    // single-edge tail: both halves see the same edge; weight half 1 to zero
    // so the cross-half combine doesn't double-count.
    if (p < e) {
        int r = srcs[p];
        float2 v = x2[(size_t)r * 32 + k];
        float t = fmaf(v.x, xn.x, v.y * xn.y);
        #pragma unroll
        for (int off = 1; off < 32; off <<= 1) t += __shfl_xor(t, off, 64);
        float wt = (half == 0) ? 1.f : 0.f;
        float ex = __expf(t * 0.125f) * wt;
        float vx = v.x * wt, vy = v.y * wt;
        den += ex;
        sx.x += vx; sx.y += vy;
        ssq.x = fmaf(vx, v.x, ssq.x); ssq.y = fmaf(vy, v.y, ssq.y);
        sme.x = fmaf(ex, v.x, sme.x); sme.y = fmaf(ex, v.y, sme.y);
    }
    // combine the two 32-lane halves (lane l and l^32 hold the same k)
    den   += __shfl_xor(den,   32, 64);
    sx.x  += __shfl_xor(sx.x,  32, 64);
    sx.y  += __shfl_xor(sx.y,  32, 64);
    ssq.x += __shfl_xor(ssq.x, 32, 64);
    ssq.y += __shfl_xor(ssq.y, 32, 64);
    sme.x += __shfl_xor(sme.x, 32, 64);
    sme.y += __shfl_xor(sme.y, 32, 64);
    float c  = (float)(e - s);
    float inv = 1.f / fmaxf(c, 1.f);
    float mx = sx.x * inv, my = sx.y * inv;
    float2 var; var.x = ssq.x * inv - mx * mx; var.y = ssq.y * inv - my * my;
    float invden = (den > 0.f) ? (1.f / den) : 0.f;
    float2 msg; msg.x = sme.x * invden; msg.y = sme.y * invden;
    if (lane < 32) {
        float2* mv = (float2*)(msgvar + (size_t)w * 128);
        mv[k]      = msg;
        mv[32 + k] = var;
    }
}

// MFMA epilogue GEMM: out = A @ Wcat^T + b, A = [x | msg | var] (N x 192).
// Block = 256 thr = 4 waves, covers 64 nodes. A-tile staged bf16 in LDS
// (64 rows x 200-short pitch). Wave w owns feature tile w (16 cols); B-frags
// (weights bf16) live in 24 VGPRs; 4 node-tiles x 6 K-steps of
// mfma_f32_16x16x32_bf16.
__global__ void __launch_bounds__(256) gemm_kernel(
        const float* __restrict__ x, const float* __restrict__ msgvar,
        const float* __restrict__ Ws, const float* __restrict__ bs,
        const float* __restrict__ Wn, const float* __restrict__ bn,
        const float* __restrict__ Wv, const float* __restrict__ bv,
        float* __restrict__ out, int N) {
    __shared__ unsigned short As[64 * 200];
    int tid = threadIdx.x;
    int nbase = blockIdx.x * 64;

    // stage x part: 64 rows x 16 float4
    #pragma unroll
    for (int i = 0; i < 4; ++i) {
        int idx = i * 256 + tid;
        int row = idx >> 4, c = idx & 15;
        int n = min(nbase + row, N - 1);
        float4 v = ((const float4*)(x + (size_t)n * 64))[c];
        ushort4 h; h.x = f2bf(v.x); h.y = f2bf(v.y); h.z = f2bf(v.z); h.w = f2bf(v.w);
        *(ushort4*)&As[row * 200 + c * 4] = h;
    }
    // stage msgvar part: 64 rows x 32 float4 (msg then var, contiguous per node)
    #pragma unroll
    for (int i = 0; i < 8; ++i) {
        int idx = i * 256 + tid;
        int row = idx >> 5, c = idx & 31;
        int n = min(nbase + row, N - 1);
        float4 v = ((const float4*)(msgvar + (size_t)n * 128))[c];
        ushort4 h; h.x = f2bf(v.x); h.y = f2bf(v.y); h.z = f2bf(v.z); h.w = f2bf(v.w);
        *(ushort4*)&As[row * 200 + 64 + c * 4] = h;
    }

    int lane = tid & 63;
    int wv = tid >> 6;                  // feature tile (wave id)
    int j = lane & 15, quad = lane >> 4;
    int jg = wv * 16 + j;               // global output feature

    // B fragments: 6 K-steps, lane holds W[jg][k0..k0+7] as bf16
    const float* Wm0[3] = {Ws, Wn, Wv};
    bf16x8 bfrag[6];
    #pragma unroll
    for (int ks = 0; ks < 6; ++ks) {
        const float* W = Wm0[ks >> 1];
        int k0 = (ks & 1) * 32 + quad * 8;
        const float4* p = (const float4*)(W + (size_t)jg * 64 + k0);
        float4 a = p[0], b = p[1];
        bf16x8 f;
        f[0] = (short)f2bf(a.x); f[1] = (short)f2bf(a.y);
        f[2] = (short)f2bf(a.z); f[3] = (short)f2bf(a.w);
        f[4] = (short)f2bf(b.x); f[5] = (short)f2bf(b.y);
        f[6] = (short)f2bf(b.z); f[7] = (short)f2bf(b.w);
        bfrag[ks] = f;
    }
    float bias = bs[jg] + bn[jg] + bv[jg];
    f32x4 acc[4];
    #pragma unroll
    for (int nt = 0; nt < 4; ++nt) { acc[nt][0] = bias; acc[nt][1] = bias; acc[nt][2] = bias; acc[nt][3] = bias; }

    __syncthreads();

    #pragma unroll
    for (int nt = 0; nt < 4; ++nt) {
        #pragma unroll
        for (int ks = 0; ks < 6; ++ks) {
            const bf16x8* ap = (const bf16x8*)&As[(nt * 16 + j) * 200 + ks * 32 + quad * 8];
            acc[nt] = __builtin_amdgcn_mfma_f32_16x16x32_bf16(*ap, bfrag[ks], acc[nt], 0, 0, 0);
        }
    }

    // D: node = nbase + nt*16 + quad*4 + r, col = jg
    #pragma unroll
    for (int nt = 0; nt < 4; ++nt) {
        #pragma unroll
        for (int r = 0; r < 4; ++r) {
            int node = nbase + nt * 16 + quad * 4 + r;
            if (node < N) out[(size_t)node * 64 + jg] = acc[nt][r];
        }
    }
}

extern "C" void kernel_launch(void* const* d_in, const int* in_sizes, int n_in,
                              void* d_out, int out_size, void* d_ws, size_t ws_size,
                              hipStream_t stream) {
    const float* x  = (const float*)d_in[0];
    const int*   ei = (const int*)d_in[1];
    const float* Ws = (const float*)d_in[2];
    const float* bs = (const float*)d_in[3];
    const float* Wn = (const float*)d_in[4];
    const float* bn = (const float*)d_in[5];
    const float* Wv = (const float*)d_in[6];
    const float* bv = (const float*)d_in[7];
    float* out = (float*)d_out;

    int N  = in_sizes[0] / 64;
    int E  = in_sizes[1] / 2;
    int NB = (N + 255) / 256;

    char* wsp = (char*)d_ws;
    size_t off = 0;
    int* deg    = (int*)(wsp + off); off += ws_align((size_t)N * 4);
    int* rs     = (int*)(wsp + off); off += ws_align((size_t)(N + 1) * 4);
    int* cursor = (int*)(wsp + off); off += ws_align((size_t)N * 4);
    int* bsumi  = (int*)(wsp + off); off += ws_align((size_t)NB * 4);
    int* srcs   = (int*)(wsp + off); off += ws_align((size_t)E * 4);
    float* msgvar = (float*)(wsp + off); off += ws_align((size_t)N * 128 * 4);

    hipMemsetAsync(deg, 0, (size_t)N * 4, stream);
    hist_kernel<<<2048, 256, 0, stream>>>(ei, deg, E, N);
    scan_a_kernel<<<NB, 256, 0, stream>>>(deg, rs, bsumi, N);
    scan_b_kernel<<<1, 512, 0, stream>>>(bsumi, NB);
    scan_c_kernel<<<(N + 255) / 256, 256, 0, stream>>>(rs, bsumi, cursor, N, E);
    scatter_kernel<<<2048, 256, 0, stream>>>(ei, cursor, srcs, E, N);
    node_gather_kernel<<<((size_t)N * 64 + 255) / 256, 256, 0, stream>>>(x, rs, srcs, msgvar, N);
    gemm_kernel<<<(N + 63) / 64, 256, 0, stream>>>(x, msgvar, Ws, bs, Wn, bn, Wv, bv, out, N);
}